// Round 1
// baseline (356.063 us; speedup 1.0000x reference)
//
#include <hip/hip_runtime.h>

// Problem: pred, target are [32,1,1024,1024] f32. Output: scalar f32 mean of
//   (softplus(pred) - pred*target) * weight
// weight = 0.1 where 5x5 window of binarized target has both a 0 and a 1
// (morphological gradient), gated on cond = (max(target)==1 && min(target)==0).
//
// Strategy: HBM-bound (268 MB min). Pack binarized target rows into bitmasks
// via __ballot (64 lanes -> one u64 word), do 5x5 dilate/erode as bit logic in
// LDS. Target read once (+halo), pred read once (float4). Double atomics for
// the two partial sums; encoded-uint atomic min/max for cond.

#define IMG   1024
#define BAND  32
#define NB    32
#define WORDS 16                     // 1024 cols / 64 bits
#define NTOT  33554432.0             // 32*1024*1024

__device__ __forceinline__ unsigned encf(float f) {
    unsigned u = __float_as_uint(f);
    return (u & 0x80000000u) ? ~u : (u | 0x80000000u);
}
__device__ __forceinline__ float decf(unsigned e) {
    unsigned u = (e & 0x80000000u) ? (e & 0x7fffffffu) : ~e;
    return __uint_as_float(u);
}

__global__ void bbl_init(double* dws, unsigned* uws) {
    if (threadIdx.x == 0) {
        dws[0] = 0.0; dws[1] = 0.0;
        uws[0] = 0xFFFFFFFFu;   // running min (encoded)
        uws[1] = 0u;            // running max (encoded)
    }
}

__global__ __launch_bounds__(256) void bbl_main(
        const float* __restrict__ pred,
        const float* __restrict__ target,
        double* __restrict__ dws, unsigned* __restrict__ uws) {
    __shared__ unsigned long long Bm[BAND + 4][WORDS];   // raw bits (t>0.5)
    __shared__ unsigned long long H1[BAND + 4][WORDS];   // horiz window has a 1
    __shared__ unsigned long long H0[BAND + 4][WORDS];   // horiz window has a 0
    __shared__ unsigned long long Em[BAND][WORDS];       // edge bits per owned row
    __shared__ float    redS1[4], redSe[4];
    __shared__ unsigned redMn[4], redMx[4];

    const int tid  = threadIdx.x;
    const int lane = tid & 63;
    const int wid  = tid >> 6;
    const int img  = blockIdx.x / (IMG / BAND);
    const int r0   = (blockIdx.x % (IMG / BAND)) * BAND;
    const int hs   = max(r0 - 2, 0);
    const int he   = min(r0 + BAND + 2, IMG);
    const int nLoaded = he - hs;

    const size_t imgBase = (size_t)img * IMG * IMG;

    float vmin = 3.4e38f, vmax = -3.4e38f;

    // ---- phase 1a: read target rows (band + halo) once, build row bitmasks
    for (int lr = wid; lr < nLoaded; lr += 4) {
        const int gr = hs + lr;
        const float* rowp = target + imgBase + (size_t)gr * IMG;
        #pragma unroll
        for (int it = 0; it < WORDS; ++it) {
            float v = rowp[it * 64 + lane];
            vmin = fminf(vmin, v); vmax = fmaxf(vmax, v);
            unsigned long long m = __ballot(v > 0.5f);
            if (lane == 0) Bm[lr][it] = m;
        }
    }
    __syncthreads();

    // ---- phase 1b: horizontal +-2 window (funnel shifts across word edges)
    for (int q = tid; q < nLoaded * WORDS; q += 256) {
        const int lr = q >> 4, w = q & 15;
        unsigned long long c = Bm[lr][w];
        unsigned long long l = (w > 0)         ? Bm[lr][w - 1] : 0ULL;
        unsigned long long r = (w < WORDS - 1) ? Bm[lr][w + 1] : 0ULL;
        unsigned long long h1 = c | (c << 1) | (l >> 63) | (c << 2) | (l >> 62)
                                  | (c >> 1) | (r << 63) | (c >> 2) | (r << 62);
        unsigned long long n  = ~c;
        unsigned long long nl = (w > 0)         ? ~l : 0ULL;   // OOB cols contribute 0
        unsigned long long nr = (w < WORDS - 1) ? ~r : 0ULL;
        unsigned long long h0 = n | (n << 1) | (nl >> 63) | (n << 2) | (nl >> 62)
                                  | (n >> 1) | (nr << 63) | (n >> 2) | (nr << 62);
        H1[lr][w] = h1; H0[lr][w] = h0;
    }
    __syncthreads();

    // ---- phase 1c: vertical OR over 5 rows -> edge = has1 & has0
    for (int q = tid; q < BAND * WORDS; q += 256) {
        const int orow = q >> 4, w = q & 15;
        const int gr = r0 + orow;
        const int lo = max(gr - 2, 0), hi = min(gr + 2, IMG - 1);
        unsigned long long a1 = 0ULL, a0 = 0ULL;
        for (int g = lo; g <= hi; ++g) { a1 |= H1[g - hs][w]; a0 |= H0[g - hs][w]; }
        Em[orow][w] = a1 & a0;
    }
    __syncthreads();

    // ---- phase 2: read pred (float4), accumulate sum(loss) and sum(loss@edge)
    float s1 = 0.f, se = 0.f;
    for (int orow = wid; orow < BAND; orow += 4) {
        const int gr = r0 + orow;
        const int lr = gr - hs;
        const float4* rowp = (const float4*)(pred + imgBase + (size_t)gr * IMG);
        #pragma unroll
        for (int it = 0; it < 4; ++it) {
            float4 p4 = rowp[it * 64 + lane];
            const int wi = it * 4 + (lane >> 4);
            const int sh = (lane & 15) * 4;
            unsigned eb = (unsigned)((Em[orow][wi] >> sh) & 0xFULL);
            unsigned tb = (unsigned)((Bm[lr][wi]  >> sh) & 0xFULL);
            float p[4] = {p4.x, p4.y, p4.z, p4.w};
            #pragma unroll
            for (int k = 0; k < 4; ++k) {
                float x = p[k];
                float t = (float)((tb >> k) & 1u);
                // stable softplus: max(x,0) + log(1+exp(-|x|))
                float loss = fmaxf(x, 0.f) + __logf(1.f + __expf(-fabsf(x))) - x * t;
                s1 += loss;
                se += ((eb >> k) & 1u) ? loss : 0.f;
            }
        }
    }

    // ---- block reduction: wave shuffle, then 4 waves via LDS, one atomic each
    for (int off = 32; off > 0; off >>= 1) {
        s1  += __shfl_down(s1, off);
        se  += __shfl_down(se, off);
        vmin = fminf(vmin, __shfl_down(vmin, off));
        vmax = fmaxf(vmax, __shfl_down(vmax, off));
    }
    if (lane == 0) {
        redS1[wid] = s1; redSe[wid] = se;
        redMn[wid] = encf(vmin); redMx[wid] = encf(vmax);
    }
    __syncthreads();
    if (tid == 0) {
        float S1 = 0.f, Se = 0.f; unsigned mn = 0xFFFFFFFFu, mx = 0u;
        for (int i = 0; i < 4; ++i) {
            S1 += redS1[i]; Se += redSe[i];
            mn = min(mn, redMn[i]); mx = max(mx, redMx[i]);
        }
        atomicAdd(&dws[0], (double)S1);
        atomicAdd(&dws[1], (double)Se);
        atomicMin(&uws[0], mn);
        atomicMax(&uws[1], mx);
    }
}

__global__ void bbl_fin(const double* __restrict__ dws,
                        const unsigned* __restrict__ uws,
                        float* __restrict__ out) {
    if (threadIdx.x == 0) {
        float fmin = decf(uws[0]);
        float fmax = decf(uws[1]);
        bool cond = (fmax == 1.0f) && (fmin == 0.0f);
        double s = cond ? (dws[0] - 0.9 * dws[1]) : dws[0];
        out[0] = (float)(s / NTOT);
    }
}

extern "C" void kernel_launch(void* const* d_in, const int* in_sizes, int n_in,
                              void* d_out, int out_size, void* d_ws, size_t ws_size,
                              hipStream_t stream) {
    const float* pred   = (const float*)d_in[0];
    const float* target = (const float*)d_in[1];
    double*   dws = (double*)d_ws;
    unsigned* uws = (unsigned*)(dws + 2);
    float*    out = (float*)d_out;

    hipLaunchKernelGGL(bbl_init, dim3(1), dim3(64), 0, stream, dws, uws);
    hipLaunchKernelGGL(bbl_main, dim3(NB * (IMG / BAND)), dim3(256), 0, stream,
                       pred, target, dws, uws);
    hipLaunchKernelGGL(bbl_fin, dim3(1), dim3(64), 0, stream, dws, uws, out);
}

// Round 2
// 296.555 us; speedup vs baseline: 1.2007x; 1.2007x over previous
//
#include <hip/hip_runtime.h>

// pred, target: [32,1,1024,1024] f32 -> scalar f32 = mean((softplus(p)-p*t)*w),
// w = 0.1 on 5x5 morphological gradient of binarized target, gated on
// cond = (t.max()==1 && t.min()==0).
//
// R2 restructure: latency-bound fix. float4 target loads; ballot per float4
// component gives mask words directly in an interleaved bit layout
// (col 256*it+4*lane+m <-> word 4*it+m, bit lane). Separable morphology:
// vertical OR/AND over 5 rows first (owned rows only), then horizontal +-2
// window = word renaming + 1-bit funnel shifts. 512-thr blocks, BAND=32,
// 1024 blocks = 4/CU, LDS ~17KB -> up to 32 waves/CU.

#define IMG     1024
#define BAND    32
#define NBANDS  (IMG / BAND)     // 32
#define NIMG    32
#define WORDS   16               // 1024 cols / 64 bits
#define HALO    2
#define MAXROWS (BAND + 2 * HALO)
#define NTOT    33554432.0

typedef unsigned long long u64;

__device__ __forceinline__ unsigned encf(float f) {
    unsigned u = __float_as_uint(f);
    return (u & 0x80000000u) ? ~u : (u | 0x80000000u);
}
__device__ __forceinline__ float decf(unsigned e) {
    unsigned u = (e & 0x80000000u) ? (e & 0x7fffffffu) : ~e;
    return __uint_as_float(u);
}

__global__ void bbl_init(double* dws, unsigned* uws) {
    if (threadIdx.x == 0) {
        dws[0] = 0.0; dws[1] = 0.0;
        uws[0] = 0xFFFFFFFFu;   // running min (encoded)
        uws[1] = 0u;            // running max (encoded)
    }
}

__global__ __launch_bounds__(512) void bbl_main(
        const float* __restrict__ pred,
        const float* __restrict__ target,
        double* __restrict__ dws, unsigned* __restrict__ uws) {
    __shared__ u64 Bm[MAXROWS][WORDS];   // raw bits (t>0.5), interleaved layout
    __shared__ u64 Vd[BAND][WORDS];      // vertical OR  (dilate, 5 rows)
    __shared__ u64 Ve[BAND][WORDS];      // vertical AND (erode, 5 rows)
    __shared__ u64 Em[BAND][WORDS];      // edge bits
    __shared__ float    redS1[8], redSe[8];
    __shared__ unsigned redMn[8], redMx[8];

    const int tid  = threadIdx.x;
    const int lane = tid & 63;
    const int wid  = tid >> 6;           // 8 waves
    const int img  = blockIdx.x / NBANDS;
    const int r0   = (blockIdx.x % NBANDS) * BAND;
    const int hs   = max(r0 - HALO, 0);
    const int he   = min(r0 + BAND + HALO, IMG);
    const int nLoaded = he - hs;
    const size_t base = (size_t)img * IMG * IMG;

    float vmin = 3.4e38f, vmax = -3.4e38f;

    // ---- 1a: stream target rows (band+halo) as float4; ballot -> mask words
    for (int lr = wid; lr < nLoaded; lr += 8) {
        const float4* rowp = (const float4*)(target + base + (size_t)(hs + lr) * IMG);
        #pragma unroll
        for (int it = 0; it < 4; ++it) {
            float4 v = rowp[it * 64 + lane];
            vmin = fminf(vmin, fminf(fminf(v.x, v.y), fminf(v.z, v.w)));
            vmax = fmaxf(vmax, fmaxf(fmaxf(v.x, v.y), fmaxf(v.z, v.w)));
            u64 b0 = __ballot(v.x > 0.5f);
            u64 b1 = __ballot(v.y > 0.5f);
            u64 b2 = __ballot(v.z > 0.5f);
            u64 b3 = __ballot(v.w > 0.5f);
            if (lane < 4) {
                u64 w = (lane == 0) ? b0 : (lane == 1) ? b1 : (lane == 2) ? b2 : b3;
                Bm[lr][it * 4 + lane] = w;
            }
        }
    }
    __syncthreads();

    // ---- 1b: vertical OR/AND over rows gr-2..gr+2 (clamped; skipped rows are
    //          identity, matching -inf/+inf reduce_window padding)
    {
        const int orow = tid >> 4, w = tid & 15;      // 32*16 = 512 = blockDim
        const int gr = r0 + orow;
        const int lo = max(gr - 2, 0), hi = min(gr + 2, IMG - 1);
        u64 vd = 0ULL, ve = ~0ULL;
        for (int g = lo; g <= hi; ++g) { u64 b = Bm[g - hs][w]; vd |= b; ve &= b; }
        Vd[orow][w] = vd; Ve[orow][w] = ve;
    }
    __syncthreads();

    // ---- 1c: horizontal +-2 in interleaved domain; edge = dilate & ~erode
    {
        const int orow = tid >> 4, w = tid & 15;
        const int k = w & 3;
        u64 hd = Vd[orow][w], he_ = Ve[orow][w];
        #pragma unroll
        for (int dd = 0; dd < 4; ++dd) {
            const int delta = (dd < 2) ? dd - 2 : dd - 1;  // -2,-1,1,2
            const int kp = k + delta;
            u64 td, te;
            if (kp >= 0 && kp <= 3) {               // same 256-block, aligned
                td = Vd[orow][w + delta];
                te = Ve[orow][w + delta];
            } else if (kp > 3) {                    // wraps toward next block
                const int wi = w + delta - 4, wn = w + delta;
                u64 nd = (wn <= 15) ? Vd[orow][wn] : 0ULL;   // OOB col: dilate id
                u64 ne = (wn <= 15) ? Ve[orow][wn] : ~0ULL;  // OOB col: erode id
                td = (Vd[orow][wi] >> 1) | (nd << 63);
                te = (Ve[orow][wi] >> 1) | (ne << 63);
            } else {                                // wraps toward prev block
                const int wi = w + delta + 4, wn = w + delta;
                u64 nd = (wn >= 0) ? Vd[orow][wn] : 0ULL;
                u64 ne = (wn >= 0) ? Ve[orow][wn] : ~0ULL;
                td = (Vd[orow][wi] << 1) | (nd >> 63);
                te = (Ve[orow][wi] << 1) | (ne >> 63);
            }
            hd |= td; he_ &= te;
        }
        Em[orow][w] = hd & ~he_;
    }
    __syncthreads();

    // ---- 2: stream pred float4; bits via LDS broadcast reads
    float s1 = 0.f, se = 0.f;
    for (int orow = wid * 4; orow < wid * 4 + 4; ++orow) {   // 8 waves x 4 rows
        const int gr = r0 + orow, lr = gr - hs;
        const float4* rowp = (const float4*)(pred + base + (size_t)gr * IMG);
        #pragma unroll
        for (int it = 0; it < 4; ++it) {
            float4 p = rowp[it * 64 + lane];
            u64 e0 = Em[orow][it * 4 + 0], e1 = Em[orow][it * 4 + 1];
            u64 e2 = Em[orow][it * 4 + 2], e3 = Em[orow][it * 4 + 3];
            u64 t0 = Bm[lr][it * 4 + 0],   t1 = Bm[lr][it * 4 + 1];
            u64 t2 = Bm[lr][it * 4 + 2],   t3 = Bm[lr][it * 4 + 3];
            float x, t, loss;
            x = p.x; t = (float)((unsigned)((t0 >> lane) & 1ULL));
            loss = fmaxf(x, 0.f) - x * t + __logf(1.f + __expf(-fabsf(x)));
            s1 += loss; se += ((e0 >> lane) & 1ULL) ? loss : 0.f;
            x = p.y; t = (float)((unsigned)((t1 >> lane) & 1ULL));
            loss = fmaxf(x, 0.f) - x * t + __logf(1.f + __expf(-fabsf(x)));
            s1 += loss; se += ((e1 >> lane) & 1ULL) ? loss : 0.f;
            x = p.z; t = (float)((unsigned)((t2 >> lane) & 1ULL));
            loss = fmaxf(x, 0.f) - x * t + __logf(1.f + __expf(-fabsf(x)));
            s1 += loss; se += ((e2 >> lane) & 1ULL) ? loss : 0.f;
            x = p.w; t = (float)((unsigned)((t3 >> lane) & 1ULL));
            loss = fmaxf(x, 0.f) - x * t + __logf(1.f + __expf(-fabsf(x)));
            s1 += loss; se += ((e3 >> lane) & 1ULL) ? loss : 0.f;
        }
    }

    // ---- reduce: wave shuffles, 8 waves via LDS, one atomic set per block
    for (int off = 32; off > 0; off >>= 1) {
        s1   += __shfl_down(s1, off);
        se   += __shfl_down(se, off);
        vmin  = fminf(vmin, __shfl_down(vmin, off));
        vmax  = fmaxf(vmax, __shfl_down(vmax, off));
    }
    if (lane == 0) {
        redS1[wid] = s1; redSe[wid] = se;
        redMn[wid] = encf(vmin); redMx[wid] = encf(vmax);
    }
    __syncthreads();
    if (tid == 0) {
        float S1 = 0.f, Se = 0.f; unsigned mn = 0xFFFFFFFFu, mx = 0u;
        #pragma unroll
        for (int i = 0; i < 8; ++i) {
            S1 += redS1[i]; Se += redSe[i];
            mn = min(mn, redMn[i]); mx = max(mx, redMx[i]);
        }
        atomicAdd(&dws[0], (double)S1);
        atomicAdd(&dws[1], (double)Se);
        atomicMin(&uws[0], mn);
        atomicMax(&uws[1], mx);
    }
}

__global__ void bbl_fin(const double* __restrict__ dws,
                        const unsigned* __restrict__ uws,
                        float* __restrict__ out) {
    if (threadIdx.x == 0) {
        float fmin = decf(uws[0]);
        float fmax = decf(uws[1]);
        bool cond = (fmax == 1.0f) && (fmin == 0.0f);
        double s = cond ? (dws[0] - 0.9 * dws[1]) : dws[0];
        out[0] = (float)(s / NTOT);
    }
}

extern "C" void kernel_launch(void* const* d_in, const int* in_sizes, int n_in,
                              void* d_out, int out_size, void* d_ws, size_t ws_size,
                              hipStream_t stream) {
    const float* pred   = (const float*)d_in[0];
    const float* target = (const float*)d_in[1];
    double*   dws = (double*)d_ws;
    unsigned* uws = (unsigned*)(dws + 2);
    float*    out = (float*)d_out;

    hipLaunchKernelGGL(bbl_init, dim3(1), dim3(64), 0, stream, dws, uws);
    hipLaunchKernelGGL(bbl_main, dim3(NIMG * NBANDS), dim3(512), 0, stream,
                       pred, target, dws, uws);
    hipLaunchKernelGGL(bbl_fin, dim3(1), dim3(64), 0, stream, dws, uws, out);
}